// Round 1
// baseline (477.680 us; speedup 1.0000x reference)
//
#include <hip/hip_runtime.h>

// GeneralizedInteractionNet on MI355X (gfx950), bf16 MFMA formulation.
//
// Reference per layer:
//   M[n,D,d]   = W[n,D,d] * h[n,d]
//   C[b,i,n,D] = sum_d Bi[b,i,d] * M[n,D,d]
//   out[b,n,D] = sum_f B0[b,f,D] * sum_i alpha[f,i,n] * C[b,i,n,D]
// Reassociated:  R[b,n,i,D] = sum_f alpha[f,i,n]*B0[b,f,D]  (GEMM2)
//                out[b,n,D] = sum_i C[b,i,n,D]*R[b,n,i,D]   (elementwise+reduce)
//
// Mapping: one wave per batch element b. mfma_f32_16x16x32_bf16 tiles:
//   rows i padded 40->48 (3 tiles), cols D=64 (4 tiles), K padded to 64 (2 steps).
//   A-frag: A[m=lane&15][k=(lane>>4)*8+j]; B-frag: B[k=(lane>>4)*8+j][n=lane&15];
//   C/D:    col=lane&15, row=(lane>>4)*4+reg.
// alphaT in ws is zero-padded (i in [40,48), f in [40,64)) so all padding
// garbage is multiplied by exact zeros.

typedef __bf16 bf16x8 __attribute__((ext_vector_type(8)));
typedef float  f32x4  __attribute__((ext_vector_type(4)));

constexpr int BATCH = 2048;
constexpr int FDIM  = 40;   // num_fields == num_subspaces
constexpr int DDIM  = 64;   // embed dim
constexpr int LAY   = 3;
constexpr int IPAD  = 48;   // i padded to 3 row tiles
constexpr int FPAD  = 64;   // f (K of GEMM2) padded to 2 K-steps

__device__ __forceinline__ unsigned short f2bf(float f) {
  union { float f; unsigned u; } v; v.f = f;
  unsigned r = v.u + 0x7fff + ((v.u >> 16) & 1);   // round-to-nearest-even
  return (unsigned short)(r >> 16);
}

__global__ void prep_b0(const float* __restrict__ in, unsigned short* __restrict__ out, int n) {
  int i = blockIdx.x * blockDim.x + threadIdx.x;
  if (i < n) out[i] = f2bf(in[i]);
}

// M[l,n,D,d] = W[l,n,D,d] * h[l,n,d]  -> bf16
__global__ void prep_M(const float* __restrict__ W, const float* __restrict__ h,
                       unsigned short* __restrict__ M) {
  int i = blockIdx.x * blockDim.x + threadIdx.x;
  if (i >= LAY * FDIM * DDIM * DDIM) return;
  int d  = i & 63;
  int ln = i >> 12;                 // l*FDIM + n
  M[i] = f2bf(W[i] * h[ln * DDIM + d]);
}

// AT[l][n][i][f] = alpha[l][f][i][n], zero-padded i->48, f->64 -> bf16
__global__ void prep_AT(const float* __restrict__ alpha, unsigned short* __restrict__ AT) {
  int i = blockIdx.x * blockDim.x + threadIdx.x;
  if (i >= LAY * FDIM * IPAD * FPAD) return;
  int f  = i & 63;
  int ii = (i >> 6) % IPAD;
  int n  = (i / (IPAD * FPAD)) % FDIM;
  int l  = i / (FDIM * IPAD * FPAD);
  float v = 0.f;
  if (f < FDIM && ii < FDIM)
    v = alpha[(((size_t)l * FDIM + f) * FDIM + ii) * FDIM + n];
  AT[i] = f2bf(v);
}

template <bool FINAL>
__global__ __launch_bounds__(256, 2) void layer_k(
    const unsigned short* __restrict__ B0,   // [B][40][64] bf16 (inputs)
    const unsigned short* __restrict__ Bi,   // [B][40][64] bf16 (prev layer)
    const unsigned short* __restrict__ Mt,   // [40][64][64] bf16 (this layer)
    const unsigned short* __restrict__ AT,   // [40][48][64] bf16 padded
    void* __restrict__ outp)                 // bf16 intermediate or f32 final
{
  const int lane = threadIdx.x & 63;
  const int b    = blockIdx.x * (blockDim.x >> 6) + (threadIdx.x >> 6);
  const int m16  = lane & 15;
  const int q    = lane >> 4;

  const unsigned short* bi_b = Bi + (size_t)b * (FDIM * DDIM);
  const unsigned short* b0_b = B0 + (size_t)b * (FDIM * DDIM);

  // Wave-constant A-frags of Bi: tile t covers rows [16t,16t+16); rows 40..47
  // read past this b's block (slack/next b) -- nullified by zero AT rows.
  bf16x8 aBi[3][2];
#pragma unroll
  for (int t = 0; t < 3; ++t)
#pragma unroll
    for (int ks = 0; ks < 2; ++ks)
      aBi[t][ks] = *reinterpret_cast<const bf16x8*>(
          bi_b + (16 * t + m16) * DDIM + ks * 32 + q * 8);

  // Wave-constant B-frags of B0 (B operand of GEMM2): B[k=f][col=D].
  // Strided gather, done once per wave (amortized over 40 n * 48 MFMA).
  // f in [40,64) reads garbage -- nullified by zero AT columns.
  bf16x8 bB0[4][2];
#pragma unroll
  for (int c = 0; c < 4; ++c)
#pragma unroll
    for (int ks = 0; ks < 2; ++ks) {
#pragma unroll
      for (int j = 0; j < 8; ++j) {
        int f = ks * 32 + q * 8 + j;
        unsigned short u = b0_b[f * DDIM + c * 16 + m16];
        bB0[c][ks][j] = __builtin_bit_cast(__bf16, u);
      }
    }

  float* outF = (float*)outp;
  unsigned short* outH = (unsigned short*)outp;

  for (int n = 0; n < FDIM; ++n) {
    const unsigned short* Mn  = Mt + n * (DDIM * DDIM);
    const unsigned short* ATn = AT + n * (IPAD * FPAD);

    // Per-n operands: M[n] B-frags (contiguous 16B/lane), alphaT A-frags.
    bf16x8 mb[4][2], at[3][2];
#pragma unroll
    for (int c = 0; c < 4; ++c)
#pragma unroll
      for (int ks = 0; ks < 2; ++ks)
        mb[c][ks] = *reinterpret_cast<const bf16x8*>(
            Mn + (16 * c + m16) * DDIM + ks * 32 + q * 8);
#pragma unroll
    for (int t = 0; t < 3; ++t)
#pragma unroll
      for (int ks = 0; ks < 2; ++ks)
        at[t][ks] = *reinterpret_cast<const bf16x8*>(
            ATn + (16 * t + m16) * FPAD + ks * 32 + q * 8);

    float p0 = 0.f, p1 = 0.f, p2 = 0.f, p3 = 0.f;
#pragma unroll
    for (int c = 0; c < 4; ++c) {
      f32x4 accC[3], accR[3];
      const f32x4 z = {0.f, 0.f, 0.f, 0.f};
#pragma unroll
      for (int t = 0; t < 3; ++t) {
        accC[t] = __builtin_amdgcn_mfma_f32_16x16x32_bf16(aBi[t][0], mb[c][0], z, 0, 0, 0);
        accC[t] = __builtin_amdgcn_mfma_f32_16x16x32_bf16(aBi[t][1], mb[c][1], accC[t], 0, 0, 0);
        accR[t] = __builtin_amdgcn_mfma_f32_16x16x32_bf16(at[t][0], bB0[c][0], z, 0, 0, 0);
        accR[t] = __builtin_amdgcn_mfma_f32_16x16x32_bf16(at[t][1], bB0[c][1], accR[t], 0, 0, 0);
      }
      // out[.,n,D] = sum_i C[i,D]*R[i,D]; per-lane partial covers rows
      // 16t + 4q + r, butterfly over quads completes the i-sum per column.
      float s = 0.f;
#pragma unroll
      for (int t = 0; t < 3; ++t)
#pragma unroll
        for (int r = 0; r < 4; ++r)
          s += accC[t][r] * accR[t][r];
      s += __shfl_xor(s, 16, 64);
      s += __shfl_xor(s, 32, 64);
      if (c == 0) p0 = s; else if (c == 1) p1 = s; else if (c == 2) p2 = s; else p3 = s;
    }
    // lane stores D = 16*q + m16 = lane  -> fully coalesced 64-wide store
    float val = (q == 0) ? p0 : (q == 1) ? p1 : (q == 2) ? p2 : p3;
    size_t off = ((size_t)b * FDIM + n) * DDIM + lane;
    if (FINAL) outF[off] = val;
    else       outH[off] = f2bf(val);
  }
}

extern "C" void kernel_launch(void* const* d_in, const int* in_sizes, int n_in,
                              void* d_out, int out_size, void* d_ws, size_t ws_size,
                              hipStream_t stream) {
  const float* inputs = (const float*)d_in[0];  // [2048,40,64]
  const float* W      = (const float*)d_in[1];  // [3,40,64,64]
  const float* alpha  = (const float*)d_in[2];  // [3,40,40,40]
  const float* h      = (const float*)d_in[3];  // [3,40,64,1]

  char* ws = (char*)d_ws;
  const size_t bufB = (size_t)BATCH * FDIM * DDIM * 2 + 8192;  // bf16 + OOB slack
  unsigned short* B0b = (unsigned short*)(ws);
  unsigned short* Bi1 = (unsigned short*)(ws + bufB);
  unsigned short* Bi2 = (unsigned short*)(ws + 2 * bufB);
  unsigned short* Mb  = (unsigned short*)(ws + 3 * bufB);
  unsigned short* ATb = (unsigned short*)(ws + 3 * bufB + (size_t)LAY * FDIM * DDIM * DDIM * 2);

  const int nB0 = BATCH * FDIM * DDIM;
  prep_b0<<<(nB0 + 255) / 256, 256, 0, stream>>>(inputs, B0b, nB0);
  const int nM = LAY * FDIM * DDIM * DDIM;
  prep_M<<<(nM + 255) / 256, 256, 0, stream>>>(W, h, Mb);
  const int nAT = LAY * FDIM * IPAD * FPAD;
  prep_AT<<<(nAT + 255) / 256, 256, 0, stream>>>(alpha, ATb);

  dim3 grid(BATCH / 4), blk(256);
  layer_k<false><<<grid, blk, 0, stream>>>(B0b, B0b, Mb, ATb, Bi1);
  layer_k<false><<<grid, blk, 0, stream>>>(B0b, Bi1,
      Mb + (size_t)1 * FDIM * DDIM * DDIM, ATb + (size_t)1 * FDIM * IPAD * FPAD, Bi2);
  layer_k<true><<<grid, blk, 0, stream>>>(B0b, Bi2,
      Mb + (size_t)2 * FDIM * DDIM * DDIM, ATb + (size_t)2 * FDIM * IPAD * FPAD, d_out);
}